// Round 4
// baseline (178.219 us; speedup 1.0000x reference)
//
#include <hip/hip_runtime.h>
#include <hip/hip_bf16.h>

// Word2MatEncoder: out[b] = prod_{t=0..63} lookup_weight[sent[b,t]] (28x28 chain)
//
// Kernel 1 (w2m_partial_mfma): 2048 one-wave blocks (256 batch x 8 seg).
//   R_t = R_{t-1} * M_t via v_mfma_f32_32x32x16_bf16 (28 padded to 32, K=28
//   -> 2 MFMAs), f32 emulated by exact truncation split x = hi + lo in pure
//   integer ops (no inline asm): (ah+al)(bh+bl) ~ ah*bh + ah*bl + al*bh,
//   6 MFMA/step. D -> next-step A relayout via a per-block LDS round-trip
//   (RL[32][34]: conflict-free writes, 2-way-free b64 reads; single wave =>
//   no barriers). B (M_t) fragments are coalesced global column loads with a
//   1-step register prefetch. Assumed A/B layout: m,n = lane&31,
//   k = 8*(lane>>5)+e (canonical CDNA); C/D layout is the m74/m101-verified
//   col=lane&31, row=(reg&3)+8*(reg>>2)+4*(lane>>5).
//
// Kernel 2 (w2m_combine): unchanged (verified R2): tree-combine 8 partials.
//   Kernel1 stores even segs transposed (A-side: buf[k*28+r] = P[r][k]),
//   odd segs row-major (B-side), matching combine's kloop convention.

typedef float f32x2  __attribute__((ext_vector_type(2)));
typedef float f32x4  __attribute__((ext_vector_type(4)));
typedef float f32x16 __attribute__((ext_vector_type(16)));
typedef short bf16x8 __attribute__((ext_vector_type(8)));

namespace {
constexpr int MD  = 28;
constexpr int EMB = 784;
constexpr int SEQ = 64;
constexpr int BATCH = 256;
constexpr int SEG = 8;
constexpr int LEN = 8;
constexpr int LDP = 34;   // LDS row pitch (floats): 2-way-free banks, 8B aligned
}

__device__ __forceinline__ bf16x8 mkfrag(uint32_t w0, uint32_t w1,
                                         uint32_t w2, uint32_t w3) {
  union { uint32_t w[4]; bf16x8 b; } u;
  u.w[0] = w0; u.w[1] = w1; u.w[2] = w2; u.w[3] = w3;
  return u.b;
}

// 8 f32 -> hi/lo bf16 fragments. Truncation split: hi = x with low 16
// mantissa bits cleared (exact), lo = x - hi (exact), lo then truncated.
__device__ __forceinline__ void split8(const float* x, bf16x8& hi, bf16x8& lo) {
  uint32_t H[4], L[4];
#pragma unroll
  for (int p = 0; p < 4; ++p) {
    float x0 = x[2 * p], x1 = x[2 * p + 1];
    uint32_t h0 = __float_as_uint(x0) & 0xffff0000u;
    uint32_t h1 = __float_as_uint(x1) & 0xffff0000u;
    float l0 = x0 - __uint_as_float(h0);
    float l1 = x1 - __uint_as_float(h1);
    H[p] = (h0 >> 16) | h1;
    L[p] = (__float_as_uint(l0) >> 16) | (__float_as_uint(l1) & 0xffff0000u);
  }
  hi = mkfrag(H[0], H[1], H[2], H[3]);
  lo = mkfrag(L[0], L[1], L[2], L[3]);
}

__global__ __launch_bounds__(64, 2)
void w2m_partial_mfma(const int* __restrict__ sent,
                      const float* __restrict__ W,
                      float* __restrict__ ws) {
  __shared__ __align__(16) float RL[32][LDP];

  const int blk   = blockIdx.x;
  const int batch = blk >> 3;
  const int seg   = blk & 7;
  const int lane  = threadIdx.x;
  const int n = lane & 31;          // A-row m / B-col n / D-col
  const int h = lane >> 5;
  const int* srow = sent + batch * SEQ + seg * LEN;

  // B fragments of M_t: b[K*8+e] = M[k][n], k = 16K + 8h + e (zero-padded)
  auto loadB = [&](const float* __restrict__ Mt, float* b) {
#pragma unroll
    for (int K = 0; K < 2; ++K)
#pragma unroll
      for (int e = 0; e < 8; ++e) {
        int k = 16 * K + 8 * h + e;
        int km = k < MD ? k : 0;
        int nm = n < MD ? n : 0;
        float t = Mt[km * MD + nm];
        b[K * 8 + e] = (k < MD && n < MD) ? t : 0.f;
      }
  };

  // A fragments of M0, direct from global (row-contiguous, 16B aligned).
  float a[16];
  {
    const float* __restrict__ M0 = W + (size_t)srow[0] * EMB;
    const int m = n;
#pragma unroll
    for (int K = 0; K < 2; ++K)
#pragma unroll
      for (int u = 0; u < 2; ++u) {
        int k0 = 16 * K + 8 * h + 4 * u;
        f32x4 v = {0.f, 0.f, 0.f, 0.f};
        if (m < MD && k0 < MD)          // chunks are fully <28 or fully >=28
          v = *reinterpret_cast<const f32x4*>(M0 + m * MD + k0);
        a[K * 8 + 4 * u + 0] = v[0];
        a[K * 8 + 4 * u + 1] = v[1];
        a[K * 8 + 4 * u + 2] = v[2];
        a[K * 8 + 4 * u + 3] = v[3];
      }
  }

  float b_nxt[16];
  loadB(W + (size_t)srow[1] * EMB, b_nxt);

  f32x16 d;
#pragma unroll
  for (int t = 1; t < LEN; ++t) {
    float b_cur[16];
#pragma unroll
    for (int q = 0; q < 16; ++q) b_cur[q] = b_nxt[q];
    if (t < LEN - 1) loadB(W + (size_t)srow[t + 1] * EMB, b_nxt);

    bf16x8 ah0, al0, ah1, al1, bh0, bl0, bh1, bl1;
    split8(a,      ah0, al0);
    split8(a + 8,  ah1, al1);
    split8(b_cur,     bh0, bl0);
    split8(b_cur + 8, bh1, bl1);

#pragma unroll
    for (int q = 0; q < 16; ++q) d[q] = 0.f;
    d = __builtin_amdgcn_mfma_f32_32x32x16_bf16(ah0, bh0, d, 0, 0, 0);
    d = __builtin_amdgcn_mfma_f32_32x32x16_bf16(ah0, bl0, d, 0, 0, 0);
    d = __builtin_amdgcn_mfma_f32_32x32x16_bf16(al0, bh0, d, 0, 0, 0);
    d = __builtin_amdgcn_mfma_f32_32x32x16_bf16(ah1, bh1, d, 0, 0, 0);
    d = __builtin_amdgcn_mfma_f32_32x32x16_bf16(ah1, bl1, d, 0, 0, 0);
    d = __builtin_amdgcn_mfma_f32_32x32x16_bf16(al1, bh1, d, 0, 0, 0);

    if (t < LEN - 1) {
      // D -> LDS row-major (conflict-free), read back A fragments (b64, 2-way free)
#pragma unroll
      for (int e = 0; e < 16; ++e) {
        int r = (e & 3) + 8 * (e >> 2) + 4 * h;
        RL[r][n] = d[e];
      }
      // single wave: no barrier needed; compiler inserts lgkmcnt waits
      const int m = n;
#pragma unroll
      for (int K = 0; K < 2; ++K)
#pragma unroll
        for (int u = 0; u < 4; ++u) {
          int k0 = 16 * K + 8 * h + 2 * u;
          f32x2 v = *reinterpret_cast<const f32x2*>(&RL[m][k0]);
          a[K * 8 + 2 * u + 0] = v[0];
          a[K * 8 + 2 * u + 1] = v[1];
        }
    }
  }

  // D = M0*...*M7 = P.  even seg: store P^T (A-side, vectorized);
  // odd seg: store P row-major (B-side, scalar).
  float* pb = ws + (size_t)(batch * SEG + seg) * EMB;
  if (n < MD) {
    if ((seg & 1) == 0) {
#pragma unroll
      for (int q = 0; q < 4; ++q) {
        int rbase = 8 * q + 4 * h;
        if (rbase < MD) {
          f32x4 v = { d[4 * q], d[4 * q + 1], d[4 * q + 2], d[4 * q + 3] };
          *reinterpret_cast<f32x4*>(pb + n * MD + rbase) = v;
        }
      }
    } else {
#pragma unroll
      for (int e = 0; e < 16; ++e) {
        int r = (e & 3) + 8 * (e >> 2) + 4 * h;
        if (r < MD) pb[r * MD + n] = d[e];
      }
    }
  }
}

// ---------------- kernel 2: unchanged (verified) ----------------

__device__ __forceinline__ void kloop(const float* __restrict__ A,
                                      const float* __restrict__ B,
                                      int r0, int c0,
                                      f32x4& a0, f32x4& a1, f32x4& a2, f32x4& a3) {
  f32x4 z = {0.f, 0.f, 0.f, 0.f};
  a0 = a1 = a2 = a3 = z;
#pragma unroll
  for (int k = 0; k < MD; ++k) {
    f32x4 rv = *reinterpret_cast<const f32x4*>(A + k * MD + r0);
    f32x4 mv = *reinterpret_cast<const f32x4*>(B + k * MD + c0);
    a0 += rv[0] * mv;
    a1 += rv[1] * mv;
    a2 += rv[2] * mv;
    a3 += rv[3] * mv;
  }
}

__device__ __forceinline__ void store_T(float* __restrict__ D, int r0, int c0,
                                        const f32x4& a0, const f32x4& a1,
                                        const f32x4& a2, const f32x4& a3) {
#pragma unroll
  for (int cc = 0; cc < 4; ++cc) {
    f32x4 v = { a0[cc], a1[cc], a2[cc], a3[cc] };
    *reinterpret_cast<f32x4*>(D + (c0 + cc) * MD + r0) = v;
  }
}

__device__ __forceinline__ void store_N(float* __restrict__ D, int r0, int c0,
                                        const f32x4& a0, const f32x4& a1,
                                        const f32x4& a2, const f32x4& a3) {
  *reinterpret_cast<f32x4*>(D + (r0 + 0) * MD + c0) = a0;
  *reinterpret_cast<f32x4*>(D + (r0 + 1) * MD + c0) = a1;
  *reinterpret_cast<f32x4*>(D + (r0 + 2) * MD + c0) = a2;
  *reinterpret_cast<f32x4*>(D + (r0 + 3) * MD + c0) = a3;
}

__global__ __launch_bounds__(256, 1)
void w2m_combine(const float* __restrict__ ws, float* __restrict__ out) {
  __shared__ __align__(16) float P[SEG][EMB];
  __shared__ __align__(16) float Q[4][EMB];
  __shared__ __align__(16) float Rl[2][EMB];

  const int batch = blockIdx.x;
  const int tid   = threadIdx.x;
  const int w     = tid >> 6;
  const int lane  = tid & 63;
  const bool act  = lane < 49;
  const int i = lane / 7, j = lane % 7;
  const int r0 = 4 * i, c0 = 4 * j;

  {
    const f32x4* src = reinterpret_cast<const f32x4*>(ws + (size_t)batch * SEG * EMB);
    f32x4* dst = reinterpret_cast<f32x4*>(&P[0][0]);
    for (int u = tid; u < SEG * EMB / 4; u += 256) dst[u] = src[u];
  }
  __syncthreads();

  f32x4 a0, a1, a2, a3;
  if (act) {
    kloop(P[2 * w], P[2 * w + 1], r0, c0, a0, a1, a2, a3);
    if (w & 1) store_N(Q[w], r0, c0, a0, a1, a2, a3);
    else       store_T(Q[w], r0, c0, a0, a1, a2, a3);
  }
  __syncthreads();
  if (w < 2 && act) {
    kloop(Q[2 * w], Q[2 * w + 1], r0, c0, a0, a1, a2, a3);
    if (w & 1) store_N(Rl[w], r0, c0, a0, a1, a2, a3);
    else       store_T(Rl[w], r0, c0, a0, a1, a2, a3);
  }
  __syncthreads();
  if (w == 0 && act) {
    kloop(Rl[0], Rl[1], r0, c0, a0, a1, a2, a3);
    store_N(out + (size_t)batch * EMB, r0, c0, a0, a1, a2, a3);
  }
}

extern "C" void kernel_launch(void* const* d_in, const int* in_sizes, int n_in,
                              void* d_out, int out_size, void* d_ws, size_t ws_size,
                              hipStream_t stream) {
  const int*   sent = (const int*)d_in[0];    // (256, 64) int32
  const float* W    = (const float*)d_in[1];  // (30001, 784) f32
  float*       out  = (float*)d_out;          // (256, 784) f32
  float*       ws   = (float*)d_ws;           // 2048*784*4 = 6.4 MB
  (void)in_sizes; (void)n_in; (void)out_size; (void)ws_size;

  w2m_partial_mfma<<<BATCH * SEG, 64, 0, stream>>>(sent, W, ws);
  w2m_combine<<<BATCH, 256, 0, stream>>>(ws, out);
}

// Round 5
// 139.159 us; speedup vs baseline: 1.2807x; 1.2807x over previous
//
#include <hip/hip_runtime.h>
#include <hip/hip_bf16.h>

// Word2MatEncoder: out[b] = prod_{t=0..63} lookup_weight[sent[b,t]] (28x28 chain)
//
// Kernel 1 (w2m_partial_mfma): 2048 one-wave blocks (256 batch x 8 seg).
//   R_t = R_{t-1} * M_t via v_mfma_f32_32x32x16_bf16, f32 emulated by exact
//   truncation split x = hi + lo (3 cross terms x 2 K-halves = 6 MFMA/step).
//   VERIFIED (R4, absmax 32): A/B layout m,n = lane&31, k = 8*(lane>>5)+e;
//   C/D layout col = lane&31, row = (reg&3)+8*(reg>>2)+4*(lane>>5).
//   R4 ran at 62us due to SCRATCH SPILLS (VGPR_Count=56 < live state; backend
//   targeted 8 waves/EU for 1-wave blocks). Fixes here:
//     - amdgpu_waves_per_eu(2,2): 256-VGPR budget, no spills (8 blocks/CU is
//       the natural occupancy anyway: 2048 blocks / 256 CU).
//     - M_t gathered with 4 coalesced f32x4 loads -> LDS double buffer;
//       B-fragments read from LDS (conflict-free; 2-way half-wave alias=free).
//       Removes 2x16-float register arrays and 16 strided global loads/step.
//   D -> next-step A relayout via LDS round trip RL[32][34] (verified R4).
//
// Kernel 2 (w2m_combine): unchanged (verified R2): tree-combine 8 partials.

typedef float f32x2  __attribute__((ext_vector_type(2)));
typedef float f32x4  __attribute__((ext_vector_type(4)));
typedef float f32x16 __attribute__((ext_vector_type(16)));
typedef short bf16x8 __attribute__((ext_vector_type(8)));

namespace {
constexpr int MD  = 28;
constexpr int EMB = 784;
constexpr int SEQ = 64;
constexpr int BATCH = 256;
constexpr int SEG = 8;
constexpr int LEN = 8;
constexpr int LDP = 34;   // RL row pitch (floats)
}

__device__ __forceinline__ bf16x8 mkfrag(uint32_t w0, uint32_t w1,
                                         uint32_t w2, uint32_t w3) {
  union { uint32_t w[4]; bf16x8 b; } u;
  u.w[0] = w0; u.w[1] = w1; u.w[2] = w2; u.w[3] = w3;
  return u.b;
}

// 8 f32 -> hi/lo bf16 fragments. Truncation split: hi = x & 0xffff0000 (exact
// bf16), lo = x - hi (exact), lo truncated to bf16.
__device__ __forceinline__ void split8(const float* x, bf16x8& hi, bf16x8& lo) {
  uint32_t H[4], L[4];
#pragma unroll
  for (int p = 0; p < 4; ++p) {
    float x0 = x[2 * p], x1 = x[2 * p + 1];
    uint32_t h0 = __float_as_uint(x0) & 0xffff0000u;
    uint32_t h1 = __float_as_uint(x1) & 0xffff0000u;
    float l0 = x0 - __uint_as_float(h0);
    float l1 = x1 - __uint_as_float(h1);
    H[p] = (h0 >> 16) | h1;
    L[p] = (__float_as_uint(l0) >> 16) | (__float_as_uint(l1) & 0xffff0000u);
  }
  hi = mkfrag(H[0], H[1], H[2], H[3]);
  lo = mkfrag(L[0], L[1], L[2], L[3]);
}

__global__ __launch_bounds__(64)
__attribute__((amdgpu_waves_per_eu(2, 2)))
void w2m_partial_mfma(const int* __restrict__ sent,
                      const float* __restrict__ W,
                      float* __restrict__ ws) {
  __shared__ __align__(16) float Ms[2][EMB];   // double-buffered gathered M_t
  __shared__ __align__(16) float RL[32][LDP];  // D -> A relayout buffer

  const int blk   = blockIdx.x;
  const int batch = blk >> 3;
  const int seg   = blk & 7;
  const int lane  = threadIdx.x;
  const int n = lane & 31;          // A-row m / B-col n / D-col
  const int h = lane >> 5;
  const int* srow = sent + batch * SEQ + seg * LEN;

  // Coalesced gather of one 28x28 matrix into a 4-register stage.
  f32x4 st0, st1, st2, st3;
  auto gstage = [&](int t) {
    const f32x4* src = reinterpret_cast<const f32x4*>(W + (size_t)srow[t] * EMB);
    st0 = src[lane];
    st1 = src[64 + lane];
    st2 = src[128 + lane];
    if (lane < 4) st3 = src[192 + lane];   // 784 = 3*256 + 16
  };
  auto lpublish = [&](int buf) {
    f32x4* d_ = reinterpret_cast<f32x4*>(Ms[buf]);
    d_[lane] = st0;
    d_[64 + lane] = st1;
    d_[128 + lane] = st2;
    if (lane < 4) d_[192 + lane] = st3;
  };

  // A fragments of M0, direct from global (row-contiguous; verified R4).
  float a[16];
  {
    const float* __restrict__ M0 = W + (size_t)srow[0] * EMB;
    const int m = n;
#pragma unroll
    for (int K = 0; K < 2; ++K)
#pragma unroll
      for (int u = 0; u < 2; ++u) {
        int k0 = 16 * K + 8 * h + 4 * u;
        f32x4 v = {0.f, 0.f, 0.f, 0.f};
        if (m < MD && k0 < MD)
          v = *reinterpret_cast<const f32x4*>(M0 + m * MD + k0);
        a[K * 8 + 4 * u + 0] = v[0];
        a[K * 8 + 4 * u + 1] = v[1];
        a[K * 8 + 4 * u + 2] = v[2];
        a[K * 8 + 4 * u + 3] = v[3];
      }
  }

  // Prologue: M1 -> Ms[1]; prefetch M2 into stage regs.
  gstage(1);
  lpublish(1);
  gstage(2);

  f32x16 d;
#pragma unroll
  for (int t = 1; t < LEN; ++t) {
    // B fragments of M_t from LDS: b[K*8+e] = M[k][n], k = 16K+8h+e.
    // Banks: fixed k -> (k*28+n)%32 distinct over n=0..31; two half-waves
    // hit different rows -> exactly 2 lanes/bank = free.
    const float* __restrict__ Mt = Ms[t & 1];
    float bb[16];
#pragma unroll
    for (int K = 0; K < 2; ++K)
#pragma unroll
      for (int e = 0; e < 8; ++e) {
        int k = 16 * K + 8 * h + e;
        int km = k < MD ? k : 0;
        int nm = n < MD ? n : 0;
        float v = Mt[km * MD + nm];
        bb[K * 8 + e] = (k < MD && n < MD) ? v : 0.f;
      }

    bf16x8 ah0, al0, ah1, al1, bh0, bl0, bh1, bl1;
    split8(a,      ah0, al0);
    split8(a + 8,  ah1, al1);
    split8(bb,     bh0, bl0);
    split8(bb + 8, bh1, bl1);

#pragma unroll
    for (int q = 0; q < 16; ++q) d[q] = 0.f;
    d = __builtin_amdgcn_mfma_f32_32x32x16_bf16(ah0, bh0, d, 0, 0, 0);
    d = __builtin_amdgcn_mfma_f32_32x32x16_bf16(ah0, bl0, d, 0, 0, 0);
    d = __builtin_amdgcn_mfma_f32_32x32x16_bf16(al0, bh0, d, 0, 0, 0);
    d = __builtin_amdgcn_mfma_f32_32x32x16_bf16(ah1, bh1, d, 0, 0, 0);
    d = __builtin_amdgcn_mfma_f32_32x32x16_bf16(ah1, bl1, d, 0, 0, 0);
    d = __builtin_amdgcn_mfma_f32_32x32x16_bf16(al1, bh1, d, 0, 0, 0);

    if (t < LEN - 1) {
      lpublish((t + 1) & 1);            // publish M_{t+1} (staged last step)
      if (t + 2 < LEN) gstage(t + 2);   // issue loads for M_{t+2}

      // D -> LDS row-major -> A fragments (verified R4; single wave, no barrier)
#pragma unroll
      for (int e = 0; e < 16; ++e) {
        int r = (e & 3) + 8 * (e >> 2) + 4 * h;
        RL[r][n] = d[e];
      }
      const int m = n;
#pragma unroll
      for (int K = 0; K < 2; ++K)
#pragma unroll
        for (int u = 0; u < 4; ++u) {
          int k0 = 16 * K + 8 * h + 2 * u;
          f32x2 v = *reinterpret_cast<const f32x2*>(&RL[m][k0]);
          a[K * 8 + 2 * u + 0] = v[0];
          a[K * 8 + 2 * u + 1] = v[1];
        }
    }
  }

  // D = M0*...*M7 = P.  even seg: store P^T (A-side, vectorized);
  // odd seg: store P row-major (B-side).  (verified R4)
  float* pb = ws + (size_t)(batch * SEG + seg) * EMB;
  if (n < MD) {
    if ((seg & 1) == 0) {
#pragma unroll
      for (int q = 0; q < 4; ++q) {
        int rbase = 8 * q + 4 * h;
        if (rbase < MD) {
          f32x4 v = { d[4 * q], d[4 * q + 1], d[4 * q + 2], d[4 * q + 3] };
          *reinterpret_cast<f32x4*>(pb + n * MD + rbase) = v;
        }
      }
    } else {
#pragma unroll
      for (int e = 0; e < 16; ++e) {
        int r = (e & 3) + 8 * (e >> 2) + 4 * h;
        if (r < MD) pb[r * MD + n] = d[e];
      }
    }
  }
}

// ---------------- kernel 2: unchanged (verified) ----------------

__device__ __forceinline__ void kloop(const float* __restrict__ A,
                                      const float* __restrict__ B,
                                      int r0, int c0,
                                      f32x4& a0, f32x4& a1, f32x4& a2, f32x4& a3) {
  f32x4 z = {0.f, 0.f, 0.f, 0.f};
  a0 = a1 = a2 = a3 = z;
#pragma unroll
  for (int k = 0; k < MD; ++k) {
    f32x4 rv = *reinterpret_cast<const f32x4*>(A + k * MD + r0);
    f32x4 mv = *reinterpret_cast<const f32x4*>(B + k * MD + c0);
    a0 += rv[0] * mv;
    a1 += rv[1] * mv;
    a2 += rv[2] * mv;
    a3 += rv[3] * mv;
  }
}

__device__ __forceinline__ void store_T(float* __restrict__ D, int r0, int c0,
                                        const f32x4& a0, const f32x4& a1,
                                        const f32x4& a2, const f32x4& a3) {
#pragma unroll
  for (int cc = 0; cc < 4; ++cc) {
    f32x4 v = { a0[cc], a1[cc], a2[cc], a3[cc] };
    *reinterpret_cast<f32x4*>(D + (c0 + cc) * MD + r0) = v;
  }
}

__device__ __forceinline__ void store_N(float* __restrict__ D, int r0, int c0,
                                        const f32x4& a0, const f32x4& a1,
                                        const f32x4& a2, const f32x4& a3) {
  *reinterpret_cast<f32x4*>(D + (r0 + 0) * MD + c0) = a0;
  *reinterpret_cast<f32x4*>(D + (r0 + 1) * MD + c0) = a1;
  *reinterpret_cast<f32x4*>(D + (r0 + 2) * MD + c0) = a2;
  *reinterpret_cast<f32x4*>(D + (r0 + 3) * MD + c0) = a3;
}

__global__ __launch_bounds__(256, 1)
void w2m_combine(const float* __restrict__ ws, float* __restrict__ out) {
  __shared__ __align__(16) float P[SEG][EMB];
  __shared__ __align__(16) float Q[4][EMB];
  __shared__ __align__(16) float Rl[2][EMB];

  const int batch = blockIdx.x;
  const int tid   = threadIdx.x;
  const int w     = tid >> 6;
  const int lane  = tid & 63;
  const bool act  = lane < 49;
  const int i = lane / 7, j = lane % 7;
  const int r0 = 4 * i, c0 = 4 * j;

  {
    const f32x4* src = reinterpret_cast<const f32x4*>(ws + (size_t)batch * SEG * EMB);
    f32x4* dst = reinterpret_cast<f32x4*>(&P[0][0]);
    for (int u = tid; u < SEG * EMB / 4; u += 256) dst[u] = src[u];
  }
  __syncthreads();

  f32x4 a0, a1, a2, a3;
  if (act) {
    kloop(P[2 * w], P[2 * w + 1], r0, c0, a0, a1, a2, a3);
    if (w & 1) store_N(Q[w], r0, c0, a0, a1, a2, a3);
    else       store_T(Q[w], r0, c0, a0, a1, a2, a3);
  }
  __syncthreads();
  if (w < 2 && act) {
    kloop(Q[2 * w], Q[2 * w + 1], r0, c0, a0, a1, a2, a3);
    if (w & 1) store_N(Rl[w], r0, c0, a0, a1, a2, a3);
    else       store_T(Rl[w], r0, c0, a0, a1, a2, a3);
  }
  __syncthreads();
  if (w == 0 && act) {
    kloop(Rl[0], Rl[1], r0, c0, a0, a1, a2, a3);
    store_N(out + (size_t)batch * EMB, r0, c0, a0, a1, a2, a3);
  }
}

extern "C" void kernel_launch(void* const* d_in, const int* in_sizes, int n_in,
                              void* d_out, int out_size, void* d_ws, size_t ws_size,
                              hipStream_t stream) {
  const int*   sent = (const int*)d_in[0];    // (256, 64) int32
  const float* W    = (const float*)d_in[1];  // (30001, 784) f32
  float*       out  = (float*)d_out;          // (256, 784) f32
  float*       ws   = (float*)d_ws;           // 2048*784*4 = 6.4 MB
  (void)in_sizes; (void)n_in; (void)out_size; (void)ws_size;

  w2m_partial_mfma<<<BATCH * SEG, 64, 0, stream>>>(sent, W, ws);
  w2m_combine<<<BATCH, 256, 0, stream>>>(ws, out);
}